// Round 1
// baseline (49.013 us; speedup 1.0000x reference)
//
#include <hip/hip_runtime.h>
#include <hip/hip_bf16.h>

typedef __attribute__((ext_vector_type(8))) short short8;
typedef __attribute__((ext_vector_type(4))) float f32x4;

#define NQ 32      // queries
#define NM 32      // query tokens
#define NH 128     // head dim
#define ND 512     // docs
#define NN 180     // doc tokens
#define NNP 192    // padded doc tokens (12 tiles of 16)
#define LSTR 136   // LDS row stride in shorts (128 + 8 pad -> 272B, kills 16-way bank conflict)

static __device__ __forceinline__ unsigned short f2bf(float x) {
  __hip_bfloat16 h = __float2bfloat16(x);
  return __builtin_bit_cast(unsigned short, h);
}

// Qb = bf16(Q * q_mask), [32*32][128]
__global__ __launch_bounds__(256, 1) void prep_q_kernel(
    const float* __restrict__ Q, const int* __restrict__ qmask,
    unsigned short* __restrict__ Qb) {
  int idx = blockIdx.x * 256 + threadIdx.x;   // float4 index, 32768 total
  int row = idx >> 5;                          // qm row (128 floats = 32 float4 per row)
  float m = (float)qmask[row];
  float4 v = reinterpret_cast<const float4*>(Q)[idx];
  unsigned int lo = (unsigned)f2bf(v.x * m) | ((unsigned)f2bf(v.y * m) << 16);
  unsigned int hi = (unsigned)f2bf(v.z * m) | ((unsigned)f2bf(v.w * m) << 16);
  reinterpret_cast<uint2*>(Qb)[idx] = make_uint2(lo, hi);
}

// one workgroup per doc d; 4 waves, each wave owns whole queries (8 q each),
// D-fragments resident in registers (12 n-tiles x 4 k-steps = 192 VGPR).
__global__ __launch_bounds__(256, 1) void maxsim_kernel(
    const float* __restrict__ D, const int* __restrict__ dmask,
    const unsigned short* __restrict__ Qb, float* __restrict__ out) {
  __shared__ unsigned short Dlds[NNP * LSTR];  // 52224 B
  const int d = blockIdx.x;
  const int tid = threadIdx.x;
  const int lane = tid & 63;
  const int wave = tid >> 6;

  // ---- stage masked D -> LDS bf16 (read fp32 coalesced float4) ----
  const float4* Dsrc = reinterpret_cast<const float4*>(D) + d * (NN * NH / 4);
  for (int i = tid; i < NN * (NH / 4); i += 256) {
    int row = i >> 5;
    int c4 = i & 31;
    float m = (float)dmask[d * NN + row];
    float4 v = Dsrc[i];
    unsigned int lo = (unsigned)f2bf(v.x * m) | ((unsigned)f2bf(v.y * m) << 16);
    unsigned int hi = (unsigned)f2bf(v.z * m) | ((unsigned)f2bf(v.w * m) << 16);
    *reinterpret_cast<uint2*>(&Dlds[row * LSTR + c4 * 4]) = make_uint2(lo, hi);
  }
  // zero the pad rows 180..191 (their sims are excluded from max anyway, but keep them finite)
  for (int i = tid; i < (NNP - NN) * (NH / 4); i += 256) {
    int row = NN + (i >> 5);
    int c4 = i & 31;
    *reinterpret_cast<uint2*>(&Dlds[row * LSTR + c4 * 4]) = make_uint2(0u, 0u);
  }
  __syncthreads();

  const int bl = lane & 15;   // fragment row/col within tile
  const int bg = lane >> 4;   // k-group

  // ---- load all B fragments once: Bf[nt][ks] = Dm[nt*16+bl][ks*32 + bg*8 .. +8] ----
  short8 Bf[12][4];
  #pragma unroll
  for (int nt = 0; nt < 12; ++nt) {
    #pragma unroll
    for (int ks = 0; ks < 4; ++ks) {
      Bf[nt][ks] = *reinterpret_cast<const short8*>(
          &Dlds[(nt * 16 + bl) * LSTR + ks * 32 + bg * 8]);
    }
  }

  // ---- each wave: its 8 queries, no barriers ----
  for (int q = wave; q < NQ; q += 4) {
    const unsigned short* Qp = Qb + q * (NM * NH);
    short8 Af[2][4];
    #pragma unroll
    for (int mt = 0; mt < 2; ++mt) {
      #pragma unroll
      for (int ks = 0; ks < 4; ++ks) {
        Af[mt][ks] = *reinterpret_cast<const short8*>(
            Qp + (mt * 16 + bl) * NH + ks * 32 + bg * 8);
      }
    }

    f32x4 run0 = {-__builtin_inff(), -__builtin_inff(), -__builtin_inff(), -__builtin_inff()};
    f32x4 run1 = run0;

    #pragma unroll
    for (int nt = 0; nt < 12; ++nt) {
      f32x4 acc0 = {0.f, 0.f, 0.f, 0.f};
      f32x4 acc1 = {0.f, 0.f, 0.f, 0.f};
      #pragma unroll
      for (int ks = 0; ks < 4; ++ks) {
        acc0 = __builtin_amdgcn_mfma_f32_16x16x32_bf16(Af[0][ks], Bf[nt][ks], acc0, 0, 0, 0);
        acc1 = __builtin_amdgcn_mfma_f32_16x16x32_bf16(Af[1][ks], Bf[nt][ks], acc1, 0, 0, 0);
      }
      // fold into running max; last tile: only cols 176..179 are real doc tokens
      const bool valid = (nt < 11) | (bl < 4);
      #pragma unroll
      for (int j = 0; j < 4; ++j) {
        float v0 = valid ? acc0[j] : -__builtin_inff();
        float v1 = valid ? acc1[j] : -__builtin_inff();
        run0[j] = fmaxf(run0[j], v0);
        run1[j] = fmaxf(run1[j], v1);
      }
    }

    // max over the 16 col-slots (lanes bl=0..15 within each k-group), then sum rows
    float sum = 0.f;
    #pragma unroll
    for (int mt = 0; mt < 2; ++mt) {
      #pragma unroll
      for (int j = 0; j < 4; ++j) {
        float v = (mt == 0) ? run0[j] : run1[j];
        v = fmaxf(v, __shfl_xor(v, 1));
        v = fmaxf(v, __shfl_xor(v, 2));
        v = fmaxf(v, __shfl_xor(v, 4));
        v = fmaxf(v, __shfl_xor(v, 8));
        sum += v;   // each lane sums its k-group's 4 rows x 2 m-tiles
      }
    }
    sum += __shfl_xor(sum, 16);  // combine the 4 k-groups (each group's lanes hold identical partials)
    sum += __shfl_xor(sum, 32);
    if (lane == 0) out[q * ND + d] = sum;
  }
}

extern "C" void kernel_launch(void* const* d_in, const int* in_sizes, int n_in,
                              void* d_out, int out_size, void* d_ws, size_t ws_size,
                              hipStream_t stream) {
  const float* Q = (const float*)d_in[0];
  const float* D = (const float*)d_in[1];
  const int* qmask = (const int*)d_in[2];
  const int* dmask = (const int*)d_in[3];
  float* out = (float*)d_out;
  unsigned short* Qb = (unsigned short*)d_ws;  // 32*32*128 bf16 = 256 KB

  prep_q_kernel<<<(NQ * NM * NH / 4) / 256, 256, 0, stream>>>(Q, qmask, Qb);
  maxsim_kernel<<<ND, 256, 0, stream>>>(D, dmask, Qb, out);
}